// Round 7
// baseline (335.665 us; speedup 1.0000x reference)
//
#include <hip/hip_runtime.h>
#include <hip/hip_bf16.h>

// Flash-attention fwd, BH=64, S=2048, D=64, scale=1/8.
// R14 = R7 structure + T1 XCD remap (kept from R13: FETCH 148->48MB proved
//       the L2-pinning mechanism) + V READ DIRECT FROM L2 (no V LDS staging).
//       setprio dropped (R13 dur regression; m190: setprio hurts barrier-
//       locked multi-wave structures).
//       Rationale: R7's largest pipe is the CU LDS unit (~54%; 64KB read +
//       16KB written per block-tile). V fragments are plain 16B/lane reads
//       of vt[bh][d][key], and with T1 each XCD's K+V working set (4MB)
//       fits its L2 exactly -> m169's "don't stage L2-resident data".
//       LDS traffic halves; staging loads halve; V loads issued at tile
//       start, consumed after QK+softmax (~1000cy cover vs ~300cy L2).
//       Direct-global V address (swizzles cancel): vt + (dt*16+l16)*2048
//       + kt*64 + quad*8 (+32 for w=1). Verified against staged path.

typedef __attribute__((ext_vector_type(8))) short short8;
typedef __attribute__((ext_vector_type(4))) short short4v;
typedef __attribute__((ext_vector_type(4))) float float4v;

#define S_LEN 2048
#define D_DIM 64
#define BH_N  64
#define LOG2E 1.4426950408889634f
#define CLF   (0.125f * LOG2E)   // folded into Q fragments

// half-up round both floats to bf16, pack into one dword (3 VALU insts)
__device__ __forceinline__ unsigned int fpack2_fast(float a, float b) {
    unsigned int ua = __builtin_bit_cast(unsigned int, a) + 0x8000u;
    unsigned int ub = __builtin_bit_cast(unsigned int, b) + 0x8000u;
    return __builtin_amdgcn_perm(ub, ua, 0x07060302);  // {ub.hi16, ua.hi16}
}
// truncate both floats to bf16 (1 VALU inst) — used for P weights only
__device__ __forceinline__ unsigned int fpack2_trunc(float a, float b) {
    return __builtin_amdgcn_perm(__builtin_bit_cast(unsigned int, b),
                                 __builtin_bit_cast(unsigned int, a),
                                 0x07060302);
}
__device__ __forceinline__ void load16_lds(const unsigned short* g, unsigned short* l) {
    __builtin_amdgcn_global_load_lds(
        (const __attribute__((address_space(1))) unsigned int*)g,
        (__attribute__((address_space(3))) unsigned int*)l,
        16, 0, 0);
}

// ---- prepass, interleaved: odd blocks convert K, even blocks transpose
//      V -> bf16 [bh][d][key], keys PERMUTED so that tile-chunk c (=4w+qd)
//      holds keys {32w+4qd..+3} ∪ {32w+16+4qd..+3} — the exact A-fragment
//      order for mfma_16x16x32 PV. ----
__global__ void __launch_bounds__(256) prep(const float* __restrict__ k,
                                            const float* __restrict__ v,
                                            unsigned short* __restrict__ kbf,
                                            unsigned short* __restrict__ vt) {
    __shared__ unsigned short T[64 * 66];    // T[d*66 + key]
    const int b = blockIdx.x;
    const int t = threadIdx.x;
    if (b & 1) {
        // ---- K convert: fully coalesced linear streaming ----
        const int kb = b >> 1;                       // 0..2047
        const size_t base = (size_t)kb * 4096;
        #pragma unroll
        for (int j = 0; j < 4; ++j) {
            const size_t i = base + (size_t)j * 1024 + (size_t)t * 4;
            const float4 f = *(const float4*)(k + i);
            uint2 w;
            w.x = fpack2_fast(f.x, f.y);
            w.y = fpack2_fast(f.z, f.w);
            *(uint2*)(kbf + i) = w;
        }
        return;
    }
    // ---- V transpose ----
    const int idx = b >> 1;                          // 0..2047
    const int kt = idx & 31, bh = idx >> 5;
    const float* Vg = v + ((size_t)bh * S_LEN + kt * 64) * D_DIM;
    #pragma unroll
    for (int it = 0; it < 4; ++it) {
        const int row = it * 16 + (t >> 4);          // key
        const int col = (t & 15) * 4;                // d
        const float4 f = *(const float4*)(Vg + row * 64 + col);
        T[(col + 0) * 66 + row] =
            (unsigned short)((__builtin_bit_cast(unsigned int, f.x) + 0x8000u) >> 16);
        T[(col + 1) * 66 + row] =
            (unsigned short)((__builtin_bit_cast(unsigned int, f.y) + 0x8000u) >> 16);
        T[(col + 2) * 66 + row] =
            (unsigned short)((__builtin_bit_cast(unsigned int, f.z) + 0x8000u) >> 16);
        T[(col + 3) * 66 + row] =
            (unsigned short)((__builtin_bit_cast(unsigned int, f.w) + 0x8000u) >> 16);
    }
    __syncthreads();
    const int d  = t >> 2;
    const int cg = t & 3;                            // chunks 2cg, 2cg+1
    uint4 o0, o1;
    {
        const int c = cg * 2, kb0 = ((c >> 2) << 5) + ((c & 3) << 2);
        const unsigned* pa = (const unsigned*)&T[d * 66 + kb0];
        const unsigned* pb = (const unsigned*)&T[d * 66 + kb0 + 16];
        o0.x = pa[0]; o0.y = pa[1]; o0.z = pb[0]; o0.w = pb[1];
    }
    {
        const int c = cg * 2 + 1, kb0 = ((c >> 2) << 5) + ((c & 3) << 2);
        const unsigned* pa = (const unsigned*)&T[d * 66 + kb0];
        const unsigned* pb = (const unsigned*)&T[d * 66 + kb0 + 16];
        o1.x = pa[0]; o1.y = pa[1]; o1.z = pb[0]; o1.w = pb[1];
    }
    unsigned short* outp = vt + ((size_t)bh * 64 + d) * S_LEN + kt * 64 + cg * 16;
    *(uint4*)(outp)     = o0;
    *(uint4*)(outp + 8) = o1;
}

// ---------------------------- main kernel ----------------------------
__global__ void __launch_bounds__(256, 4) attn_fwd14(
        const float* __restrict__ q, const unsigned short* __restrict__ kbf,
        const unsigned short* __restrict__ vt, float* __restrict__ out) {
    __shared__ __align__(16) unsigned short Klds[2][64 * 64];   // K only, 16 KB

    const int tid  = threadIdx.x;
    const int lane = tid & 63;
    const int wave = tid >> 6;
    const int l16  = lane & 15;
    const int quad = lane >> 4;
    const int rsw  = l16 & 7;

    // T1: XCD-locality decode. bh = lid&63 -> XCD(lid%8)==bh%8, so all 16
    // q-blocks of a bh share one XCD's L2 (8 bh x 512KB = 4MB, L2-exact).
    const int lid   = blockIdx.x;
    const int bh    = lid & 63;
    const int qbase = (lid >> 6) * 128;

    const unsigned short* Kb = kbf + (size_t)bh * S_LEN * D_DIM;
    const unsigned short* Vb = vt  + (size_t)bh * D_DIM * S_LEN;

    // Q fragments for 2 q-sets; scale*log2e folded so p = exp2(score).
    short8 qf[2][2];
    #pragma unroll
    for (int s = 0; s < 2; ++s) {
        const int qg = qbase + s * 64 + wave * 16 + l16;
        const float* Qr = q + ((size_t)bh * S_LEN + qg) * D_DIM;
        #pragma unroll
        for (int h = 0; h < 2; ++h) {
            const float4 a = *(const float4*)(Qr + h * 32 + quad * 8);
            const float4 b = *(const float4*)(Qr + h * 32 + quad * 8 + 4);
            uint4 w;
            w.x = fpack2_fast(a.x * CLF, a.y * CLF);
            w.y = fpack2_fast(a.z * CLF, a.w * CLF);
            w.z = fpack2_fast(b.x * CLF, b.y * CLF);
            w.w = fpack2_fast(b.z * CLF, b.w * CLF);
            qf[s][h] = __builtin_bit_cast(short8, w);
        }
    }

    const int srow0  = wave * 16 + (lane >> 3);
    const int schunk = (lane & 7) ^ (lane >> 3);
    const int dsoff  = wave * 1024 + lane * 8;       // linear LDS dest slot
    const int p0     = (quad ^ rsw) * 8;             // swizzled frag offset

    // per-lane V base: row (d) = dt*16 + l16, key chunk = quad*8 (+32 w=1)
    const unsigned short* Vlane = Vb + (size_t)l16 * S_LEN + quad * 8;

    float4v acc[2][4];
    #pragma unroll
    for (int s = 0; s < 2; ++s)
        #pragma unroll
        for (int dt = 0; dt < 4; ++dt) acc[s][dt] = (float4v){0.f, 0.f, 0.f, 0.f};
    float l_acc[2] = {0.f, 0.f};

    // stage K tile kt into buffer buf (2 loads/wave)
    auto stage = [&](int kt, int buf) {
        #pragma unroll
        for (int ss = 0; ss < 2; ++ss) {
            const int row = srow0 + ss * 8;
            load16_lds(Kb + ((size_t)(kt * 64 + row)) * 64 + schunk * 8,
                       &Klds[buf][dsoff + ss * 512]);
        }
    };

    // compute one 64-key tile; K from LDS buf, V direct from global (L2)
    auto tile = [&](int buf, int kt) {
        // ---- V fragments: issue early, consumed only after QK+softmax ----
        short8 vf[4][2];
        #pragma unroll
        for (int dt = 0; dt < 4; ++dt) {
            const unsigned short* vg = Vlane + (size_t)(dt * 16) * S_LEN + kt * 64;
            vf[dt][0] = *(const short8*)(vg);
            vf[dt][1] = *(const short8*)(vg + 32);
        }
        // ---- QK^T ----
        float4v st[2][4];
        #pragma unroll
        for (int ks = 0; ks < 4; ++ks) {
            const unsigned short* kr = &Klds[buf][(ks * 16 + l16) * 64];
            const short8 kf0 = *(const short8*)(kr + p0);
            const short8 kf1 = *(const short8*)(kr + (p0 ^ 32));
            #pragma unroll
            for (int s = 0; s < 2; ++s) {
                float4v z = (float4v){0.f, 0.f, 0.f, 0.f};
                z = __builtin_amdgcn_mfma_f32_16x16x32_bf16(kf0, qf[s][0], z, 0, 0, 0);
                z = __builtin_amdgcn_mfma_f32_16x16x32_bf16(kf1, qf[s][1], z, 0, 0, 0);
                st[s][ks] = z;
            }
        }
        // ---- softmax: p = exp2(score); build x32 B-fragments pf8[s][w] ----
        short8 pf8[2][2];
        #pragma unroll
        for (int s = 0; s < 2; ++s) {
            #pragma unroll
            for (int w = 0; w < 2; ++w) {
                const float e0 = __builtin_amdgcn_exp2f(st[s][2*w][0]);
                const float e1 = __builtin_amdgcn_exp2f(st[s][2*w][1]);
                const float e2 = __builtin_amdgcn_exp2f(st[s][2*w][2]);
                const float e3 = __builtin_amdgcn_exp2f(st[s][2*w][3]);
                const float f0 = __builtin_amdgcn_exp2f(st[s][2*w+1][0]);
                const float f1 = __builtin_amdgcn_exp2f(st[s][2*w+1][1]);
                const float f2 = __builtin_amdgcn_exp2f(st[s][2*w+1][2]);
                const float f3 = __builtin_amdgcn_exp2f(st[s][2*w+1][3]);
                l_acc[s] += ((e0 + e1) + (e2 + e3)) + ((f0 + f1) + (f2 + f3));
                uint4 u;
                u.x = fpack2_trunc(e0, e1); u.y = fpack2_trunc(e2, e3);
                u.z = fpack2_trunc(f0, f1); u.w = fpack2_trunc(f2, f3);
                pf8[s][w] = __builtin_bit_cast(short8, u);
            }
        }
        // ---- O^T += V^T · P^T on x32 (V from registers) ----
        #pragma unroll
        for (int dt = 0; dt < 4; ++dt) {
            #pragma unroll
            for (int s = 0; s < 2; ++s) {
                acc[s][dt] = __builtin_amdgcn_mfma_f32_16x16x32_bf16(vf[dt][0], pf8[s][0], acc[s][dt], 0, 0, 0);
                acc[s][dt] = __builtin_amdgcn_mfma_f32_16x16x32_bf16(vf[dt][1], pf8[s][1], acc[s][dt], 0, 0, 0);
            }
        }
    };

    stage(0, 0);
    #pragma unroll 1
    for (int kt = 0; kt < S_LEN / 64; kt += 2) {
        __syncthreads();                 // buf0 (tile kt) staged; prior reads done
        stage(kt + 1, 1);                // fly during tile kt compute
        tile(0, kt);
        __syncthreads();                 // buf1 (tile kt+1) staged
        if (kt + 2 < S_LEN / 64) stage(kt + 2, 0);
        tile(1, kt + 1);
    }

    #pragma unroll
    for (int s = 0; s < 2; ++s) {
        float l = l_acc[s];
        l += __shfl_xor(l, 16, 64);
        l += __shfl_xor(l, 32, 64);
        const float inv = 1.0f / l;
        const int qg = qbase + s * 64 + wave * 16 + l16;
        float* Or = out + ((size_t)bh * S_LEN + qg) * D_DIM;
        #pragma unroll
        for (int dt = 0; dt < 4; ++dt) {
            float4 o;
            o.x = acc[s][dt][0] * inv; o.y = acc[s][dt][1] * inv;
            o.z = acc[s][dt][2] * inv; o.w = acc[s][dt][3] * inv;
            *(float4*)(Or + dt * 16 + quad * 4) = o;
        }
    }
}

// ---------------- fallback (ws too small): fused kernel ----------------
#define KSTRIDE 72
__global__ void __launch_bounds__(256) attn_fwd(
        const float* __restrict__ q, const float* __restrict__ k,
        const float* __restrict__ v, float* __restrict__ out) {
    __shared__ __align__(16) unsigned short Klds[64 * KSTRIDE];
    __shared__ __align__(16) unsigned short Vlds[64 * KSTRIDE];
    const int tid  = threadIdx.x;
    const int lane = tid & 63;
    const int wave = tid >> 6;
    const int l16  = lane & 15;
    const int quad = lane >> 4;
    const int bh    = blockIdx.y;
    const int qg    = blockIdx.x * 64 + wave * 16 + l16;
    const float* Qr = q + ((size_t)bh * S_LEN + qg) * D_DIM;
    const float* Kb = k + (size_t)bh * S_LEN * D_DIM;
    const float* Vb = v + (size_t)bh * S_LEN * D_DIM;
    short8 qf[2];
    #pragma unroll
    for (int h = 0; h < 2; ++h) {
        const float4 a = *(const float4*)(Qr + h * 32 + quad * 8);
        const float4 b = *(const float4*)(Qr + h * 32 + quad * 8 + 4);
        uint4 w;
        w.x = fpack2_fast(a.x * CLF, a.y * CLF);
        w.y = fpack2_fast(a.z * CLF, a.w * CLF);
        w.z = fpack2_fast(b.x * CLF, b.y * CLF);
        w.w = fpack2_fast(b.z * CLF, b.w * CLF);
        qf[h] = __builtin_bit_cast(short8, w);
    }
    float4v acc[4];
    #pragma unroll
    for (int dt = 0; dt < 4; ++dt) acc[dt] = (float4v){0.f, 0.f, 0.f, 0.f};
    float l_acc = 0.f;
    for (int kt = 0; kt < S_LEN / 64; ++kt) {
        __syncthreads();
        {
            const float* Kg = Kb + (size_t)kt * 64 * D_DIM;
            #pragma unroll
            for (int i = 0; i < 4; ++i) {
                const int idx = tid + i * 256;
                const int row = idx >> 4;
                const int col = (idx & 15) << 2;
                const float4 f = *(const float4*)(Kg + row * 64 + col);
                uint2 w; w.x = fpack2_fast(f.x, f.y); w.y = fpack2_fast(f.z, f.w);
                *(uint2*)(&Klds[row * KSTRIDE + col]) = w;
            }
        }
        {
            const float* Vg = Vb + (size_t)kt * 64 * D_DIM;
            #pragma unroll
            for (int it = 0; it < 2; ++it) {
                const int rp   = (tid & 15) + (it << 4);
                const int cg   = tid >> 4;
                const int row0 = rp * 2;
                const int col  = cg * 4;
                const float4 a = *(const float4*)(Vg + row0 * 64 + col);
                const float4 b = *(const float4*)(Vg + (row0 + 1) * 64 + col);
                *(unsigned int*)(&Vlds[(col + 0) * KSTRIDE + row0]) = fpack2_fast(a.x, b.x);
                *(unsigned int*)(&Vlds[(col + 1) * KSTRIDE + row0]) = fpack2_fast(a.y, b.y);
                *(unsigned int*)(&Vlds[(col + 2) * KSTRIDE + row0]) = fpack2_fast(a.z, b.z);
                *(unsigned int*)(&Vlds[(col + 3) * KSTRIDE + row0]) = fpack2_fast(a.w, b.w);
            }
        }
        __syncthreads();
        float4v st[4];
        #pragma unroll
        for (int ks = 0; ks < 4; ++ks) {
            const unsigned short* kr = &Klds[(ks * 16 + l16) * KSTRIDE + quad * 8];
            const short8 kf0 = *(const short8*)(kr);
            const short8 kf1 = *(const short8*)(kr + 32);
            float4v z = (float4v){0.f, 0.f, 0.f, 0.f};
            z = __builtin_amdgcn_mfma_f32_16x16x32_bf16(kf0, qf[0], z, 0, 0, 0);
            z = __builtin_amdgcn_mfma_f32_16x16x32_bf16(kf1, qf[1], z, 0, 0, 0);
            st[ks] = z;
        }
        short4v pf[4];
        #pragma unroll
        for (int ks = 0; ks < 4; ++ks) {
            const float p0 = __builtin_amdgcn_exp2f(st[ks][0]);
            const float p1 = __builtin_amdgcn_exp2f(st[ks][1]);
            const float p2 = __builtin_amdgcn_exp2f(st[ks][2]);
            const float p3 = __builtin_amdgcn_exp2f(st[ks][3]);
            l_acc += (p0 + p1) + (p2 + p3);
            uint2 u; u.x = fpack2_trunc(p0, p1); u.y = fpack2_trunc(p2, p3);
            pf[ks] = __builtin_bit_cast(short4v, u);
        }
        #pragma unroll
        for (int dt = 0; dt < 4; ++dt) {
            const unsigned short* vr = &Vlds[(dt * 16 + l16) * KSTRIDE + quad * 4];
            #pragma unroll
            for (int ks = 0; ks < 4; ++ks) {
                const short4v vf = *(const short4v*)(vr + ks * 16);
                acc[dt] = __builtin_amdgcn_mfma_f32_16x16x16bf16_1k(vf, pf[ks], acc[dt], 0, 0, 0);
            }
        }
    }
    float l = l_acc;
    l += __shfl_xor(l, 16, 64);
    l += __shfl_xor(l, 32, 64);
    const float inv = 1.0f / l;
    float* Or = out + ((size_t)bh * S_LEN + qg) * D_DIM;
    #pragma unroll
    for (int dt = 0; dt < 4; ++dt) {
        float4 o;
        o.x = acc[dt][0] * inv; o.y = acc[dt][1] * inv;
        o.z = acc[dt][2] * inv; o.w = acc[dt][3] * inv;
        *(float4*)(Or + dt * 16 + quad * 4) = o;
    }
}

extern "C" void kernel_launch(void* const* d_in, const int* in_sizes, int n_in,
                              void* d_out, int out_size, void* d_ws, size_t ws_size,
                              hipStream_t stream) {
    const float* q = (const float*)d_in[0];
    const float* k = (const float*)d_in[1];
    const float* v = (const float*)d_in[2];
    float* out = (float*)d_out;
    const size_t need = (size_t)2 * BH_N * S_LEN * D_DIM * sizeof(unsigned short);
    if (ws_size >= need) {
        unsigned short* kbf = (unsigned short*)d_ws;
        unsigned short* vtp = kbf + (size_t)BH_N * S_LEN * D_DIM;
        prep<<<dim3(4096), 256, 0, stream>>>(k, v, kbf, vtp);
        attn_fwd14<<<dim3((S_LEN / 128) * BH_N), 256, 0, stream>>>(q, kbf, vtp, out);
    } else {
        attn_fwd<<<dim3(S_LEN / 64, BH_N), 256, 0, stream>>>(q, k, v, out);
    }
}

// Round 8
// 197.567 us; speedup vs baseline: 1.6990x; 1.6990x over previous
//
#include <hip/hip_runtime.h>
#include <hip/hip_bf16.h>

// Flash-attention fwd, BH=64, S=2048, D=64, scale=1/8.
// R15 = R12 attn (exact R7 champion structure: K+V double-buffered
//       global_load_lds staging, 1 barrier/tile, x32 PV via permuted Vt)
//       + T1 XCD remap ONLY (grid flattened; bh = lid&63 so all 16
//       q-blocks sharing a bh's K/V pin to one XCD L2 — R13 proved
//       FETCH 148.7->47.7MB). setprio dropped (m190: negative on
//       barrier-locked multi-wave; R13 bundled it, -15%). V stays in LDS
//       (R14's V-in-regs spilled: WRITE 408MB — no reg headroom at
//       (256,4); that family is closed).
//       Single-lever isolation: dur <=86 keep (drain shrink real);
//       88-92 neutral (latency already TLP-hidden); >95 revert T1.

typedef __attribute__((ext_vector_type(8))) short short8;
typedef __attribute__((ext_vector_type(4))) short short4v;
typedef __attribute__((ext_vector_type(4))) float float4v;

#define S_LEN 2048
#define D_DIM 64
#define BH_N  64
#define LOG2E 1.4426950408889634f
#define CLF   (0.125f * LOG2E)   // folded into Q fragments

// half-up round both floats to bf16, pack into one dword (3 VALU insts)
__device__ __forceinline__ unsigned int fpack2_fast(float a, float b) {
    unsigned int ua = __builtin_bit_cast(unsigned int, a) + 0x8000u;
    unsigned int ub = __builtin_bit_cast(unsigned int, b) + 0x8000u;
    return __builtin_amdgcn_perm(ub, ua, 0x07060302);  // {ub.hi16, ua.hi16}
}
// truncate both floats to bf16 (1 VALU inst) — used for P weights only
__device__ __forceinline__ unsigned int fpack2_trunc(float a, float b) {
    return __builtin_amdgcn_perm(__builtin_bit_cast(unsigned int, b),
                                 __builtin_bit_cast(unsigned int, a),
                                 0x07060302);
}
__device__ __forceinline__ void load16_lds(const unsigned short* g, unsigned short* l) {
    __builtin_amdgcn_global_load_lds(
        (const __attribute__((address_space(1))) unsigned int*)g,
        (__attribute__((address_space(3))) unsigned int*)l,
        16, 0, 0);
}

// ---- prepass, interleaved: odd blocks convert K, even blocks transpose
//      V -> bf16 [bh][d][key], keys PERMUTED so that tile-chunk c (=4w+qd)
//      holds keys {32w+4qd..+3} ∪ {32w+16+4qd..+3} — the exact A-fragment
//      order for mfma_16x16x32 PV. ----
__global__ void __launch_bounds__(256) prep(const float* __restrict__ k,
                                            const float* __restrict__ v,
                                            unsigned short* __restrict__ kbf,
                                            unsigned short* __restrict__ vt) {
    __shared__ unsigned short T[64 * 66];    // T[d*66 + key]
    const int b = blockIdx.x;
    const int t = threadIdx.x;
    if (b & 1) {
        // ---- K convert: fully coalesced linear streaming ----
        const int kb = b >> 1;                       // 0..2047
        const size_t base = (size_t)kb * 4096;
        #pragma unroll
        for (int j = 0; j < 4; ++j) {
            const size_t i = base + (size_t)j * 1024 + (size_t)t * 4;
            const float4 f = *(const float4*)(k + i);
            uint2 w;
            w.x = fpack2_fast(f.x, f.y);
            w.y = fpack2_fast(f.z, f.w);
            *(uint2*)(kbf + i) = w;
        }
        return;
    }
    // ---- V transpose ----
    const int idx = b >> 1;                          // 0..2047
    const int kt = idx & 31, bh = idx >> 5;
    const float* Vg = v + ((size_t)bh * S_LEN + kt * 64) * D_DIM;
    #pragma unroll
    for (int it = 0; it < 4; ++it) {
        const int row = it * 16 + (t >> 4);          // key
        const int col = (t & 15) * 4;                // d
        const float4 f = *(const float4*)(Vg + row * 64 + col);
        T[(col + 0) * 66 + row] =
            (unsigned short)((__builtin_bit_cast(unsigned int, f.x) + 0x8000u) >> 16);
        T[(col + 1) * 66 + row] =
            (unsigned short)((__builtin_bit_cast(unsigned int, f.y) + 0x8000u) >> 16);
        T[(col + 2) * 66 + row] =
            (unsigned short)((__builtin_bit_cast(unsigned int, f.z) + 0x8000u) >> 16);
        T[(col + 3) * 66 + row] =
            (unsigned short)((__builtin_bit_cast(unsigned int, f.w) + 0x8000u) >> 16);
    }
    __syncthreads();
    const int d  = t >> 2;
    const int cg = t & 3;                            // chunks 2cg, 2cg+1
    uint4 o0, o1;
    {
        const int c = cg * 2, kb0 = ((c >> 2) << 5) + ((c & 3) << 2);
        const unsigned* pa = (const unsigned*)&T[d * 66 + kb0];
        const unsigned* pb = (const unsigned*)&T[d * 66 + kb0 + 16];
        o0.x = pa[0]; o0.y = pa[1]; o0.z = pb[0]; o0.w = pb[1];
    }
    {
        const int c = cg * 2 + 1, kb0 = ((c >> 2) << 5) + ((c & 3) << 2);
        const unsigned* pa = (const unsigned*)&T[d * 66 + kb0];
        const unsigned* pb = (const unsigned*)&T[d * 66 + kb0 + 16];
        o1.x = pa[0]; o1.y = pa[1]; o1.z = pb[0]; o1.w = pb[1];
    }
    unsigned short* outp = vt + ((size_t)bh * 64 + d) * S_LEN + kt * 64 + cg * 16;
    *(uint4*)(outp)     = o0;
    *(uint4*)(outp + 8) = o1;
}

// ---------------------------- main kernel ----------------------------
__global__ void __launch_bounds__(256, 4) attn_fwd15(
        const float* __restrict__ q, const unsigned short* __restrict__ kbf,
        const unsigned short* __restrict__ vt, float* __restrict__ out) {
    __shared__ __align__(16) unsigned short Klds[2][64 * 64];
    __shared__ __align__(16) unsigned short Vlds[2][64 * 64];

    const int tid  = threadIdx.x;
    const int lane = tid & 63;
    const int wave = tid >> 6;
    const int l16  = lane & 15;
    const int quad = lane >> 4;
    const int rsw  = l16 & 7;

    // T1: XCD-locality decode. bh = lid&63 -> XCD(lid%8)==bh%8, so all 16
    // q-blocks of a bh share one XCD's L2 (8 bh x 512KB = 4MB).
    const int lid   = blockIdx.x;
    const int bh    = lid & 63;
    const int qbase = (lid >> 6) * 128;

    const unsigned short* Kb = kbf + (size_t)bh * S_LEN * D_DIM;
    const unsigned short* Vb = vt  + (size_t)bh * D_DIM * S_LEN;

    // Q fragments for 2 q-sets; scale*log2e folded so p = exp2(score).
    short8 qf[2][2];
    #pragma unroll
    for (int s = 0; s < 2; ++s) {
        const int qg = qbase + s * 64 + wave * 16 + l16;
        const float* Qr = q + ((size_t)bh * S_LEN + qg) * D_DIM;
        #pragma unroll
        for (int h = 0; h < 2; ++h) {
            const float4 a = *(const float4*)(Qr + h * 32 + quad * 8);
            const float4 b = *(const float4*)(Qr + h * 32 + quad * 8 + 4);
            uint4 w;
            w.x = fpack2_fast(a.x * CLF, a.y * CLF);
            w.y = fpack2_fast(a.z * CLF, a.w * CLF);
            w.z = fpack2_fast(b.x * CLF, b.y * CLF);
            w.w = fpack2_fast(b.z * CLF, b.w * CLF);
            qf[s][h] = __builtin_bit_cast(short8, w);
        }
    }

    const int srow0  = wave * 16 + (lane >> 3);
    const int schunk = (lane & 7) ^ (lane >> 3);
    const int dsoff  = wave * 1024 + lane * 8;       // linear LDS dest slot
    const int p0     = (quad ^ rsw) * 8;             // swizzled frag offset

    float4v acc[2][4];
    #pragma unroll
    for (int s = 0; s < 2; ++s)
        #pragma unroll
        for (int dt = 0; dt < 4; ++dt) acc[s][dt] = (float4v){0.f, 0.f, 0.f, 0.f};
    float l_acc[2] = {0.f, 0.f};

    // stage tile kt into buffer buf
    auto stage = [&](int kt, int buf) {
        #pragma unroll
        for (int ss = 0; ss < 2; ++ss) {
            const int row = srow0 + ss * 8;
            load16_lds(Kb + ((size_t)(kt * 64 + row)) * 64 + schunk * 8,
                       &Klds[buf][dsoff + ss * 512]);
            load16_lds(Vb + (size_t)row * S_LEN + kt * 64 + schunk * 8,
                       &Vlds[buf][dsoff + ss * 512]);
        }
    };

    // compute one 64-key tile from buffer buf
    auto tile = [&](int buf) {
        // ---- QK^T ----
        float4v st[2][4];
        #pragma unroll
        for (int ks = 0; ks < 4; ++ks) {
            const unsigned short* kr = &Klds[buf][(ks * 16 + l16) * 64];
            const short8 kf0 = *(const short8*)(kr + p0);
            const short8 kf1 = *(const short8*)(kr + (p0 ^ 32));
            #pragma unroll
            for (int s = 0; s < 2; ++s) {
                float4v z = (float4v){0.f, 0.f, 0.f, 0.f};
                z = __builtin_amdgcn_mfma_f32_16x16x32_bf16(kf0, qf[s][0], z, 0, 0, 0);
                z = __builtin_amdgcn_mfma_f32_16x16x32_bf16(kf1, qf[s][1], z, 0, 0, 0);
                st[s][ks] = z;
            }
        }
        // ---- softmax: p = exp2(score); build x32 B-fragments pf8[s][w] ----
        short8 pf8[2][2];
        #pragma unroll
        for (int s = 0; s < 2; ++s) {
            #pragma unroll
            for (int w = 0; w < 2; ++w) {
                const float e0 = __builtin_amdgcn_exp2f(st[s][2*w][0]);
                const float e1 = __builtin_amdgcn_exp2f(st[s][2*w][1]);
                const float e2 = __builtin_amdgcn_exp2f(st[s][2*w][2]);
                const float e3 = __builtin_amdgcn_exp2f(st[s][2*w][3]);
                const float f0 = __builtin_amdgcn_exp2f(st[s][2*w+1][0]);
                const float f1 = __builtin_amdgcn_exp2f(st[s][2*w+1][1]);
                const float f2 = __builtin_amdgcn_exp2f(st[s][2*w+1][2]);
                const float f3 = __builtin_amdgcn_exp2f(st[s][2*w+1][3]);
                l_acc[s] += ((e0 + e1) + (e2 + e3)) + ((f0 + f1) + (f2 + f3));
                uint4 u;
                u.x = fpack2_trunc(e0, e1); u.y = fpack2_trunc(e2, e3);
                u.z = fpack2_trunc(f0, f1); u.w = fpack2_trunc(f2, f3);
                pf8[s][w] = __builtin_bit_cast(short8, u);
            }
        }
        // ---- O^T += V^T · P^T on x32 ----
        #pragma unroll
        for (int dt = 0; dt < 4; ++dt) {
            const unsigned short* vrow = &Vlds[buf][(dt * 16 + l16) * 64];
            const short8 vf0 = *(const short8*)(vrow + p0);          // w=0
            const short8 vf1 = *(const short8*)(vrow + (p0 ^ 32));   // w=1
            #pragma unroll
            for (int s = 0; s < 2; ++s) {
                acc[s][dt] = __builtin_amdgcn_mfma_f32_16x16x32_bf16(vf0, pf8[s][0], acc[s][dt], 0, 0, 0);
                acc[s][dt] = __builtin_amdgcn_mfma_f32_16x16x32_bf16(vf1, pf8[s][1], acc[s][dt], 0, 0, 0);
            }
        }
    };

    stage(0, 0);
    #pragma unroll 1
    for (int kt = 0; kt < S_LEN / 64; kt += 2) {
        __syncthreads();                 // buf0 (tile kt) staged; prior reads done
        stage(kt + 1, 1);                // fly during tile kt compute
        tile(0);
        __syncthreads();                 // buf1 (tile kt+1) staged
        if (kt + 2 < S_LEN / 64) stage(kt + 2, 0);
        tile(1);
    }

    #pragma unroll
    for (int s = 0; s < 2; ++s) {
        float l = l_acc[s];
        l += __shfl_xor(l, 16, 64);
        l += __shfl_xor(l, 32, 64);
        const float inv = 1.0f / l;
        const int qg = qbase + s * 64 + wave * 16 + l16;
        float* Or = out + ((size_t)bh * S_LEN + qg) * D_DIM;
        #pragma unroll
        for (int dt = 0; dt < 4; ++dt) {
            float4 o;
            o.x = acc[s][dt][0] * inv; o.y = acc[s][dt][1] * inv;
            o.z = acc[s][dt][2] * inv; o.w = acc[s][dt][3] * inv;
            *(float4*)(Or + dt * 16 + quad * 4) = o;
        }
    }
}

// ---------------- fallback (ws too small): fused kernel ----------------
#define KSTRIDE 72
__global__ void __launch_bounds__(256) attn_fwd(
        const float* __restrict__ q, const float* __restrict__ k,
        const float* __restrict__ v, float* __restrict__ out) {
    __shared__ __align__(16) unsigned short Klds[64 * KSTRIDE];
    __shared__ __align__(16) unsigned short Vlds[64 * KSTRIDE];
    const int tid  = threadIdx.x;
    const int lane = tid & 63;
    const int wave = tid >> 6;
    const int l16  = lane & 15;
    const int quad = lane >> 4;
    const int bh    = blockIdx.y;
    const int qg    = blockIdx.x * 64 + wave * 16 + l16;
    const float* Qr = q + ((size_t)bh * S_LEN + qg) * D_DIM;
    const float* Kb = k + (size_t)bh * S_LEN * D_DIM;
    const float* Vb = v + (size_t)bh * S_LEN * D_DIM;
    short8 qf[2];
    #pragma unroll
    for (int h = 0; h < 2; ++h) {
        const float4 a = *(const float4*)(Qr + h * 32 + quad * 8);
        const float4 b = *(const float4*)(Qr + h * 32 + quad * 8 + 4);
        uint4 w;
        w.x = fpack2_fast(a.x * CLF, a.y * CLF);
        w.y = fpack2_fast(a.z * CLF, a.w * CLF);
        w.z = fpack2_fast(b.x * CLF, b.y * CLF);
        w.w = fpack2_fast(b.z * CLF, b.w * CLF);
        qf[h] = __builtin_bit_cast(short8, w);
    }
    float4v acc[4];
    #pragma unroll
    for (int dt = 0; dt < 4; ++dt) acc[dt] = (float4v){0.f, 0.f, 0.f, 0.f};
    float l_acc = 0.f;
    for (int kt = 0; kt < S_LEN / 64; ++kt) {
        __syncthreads();
        {
            const float* Kg = Kb + (size_t)kt * 64 * D_DIM;
            #pragma unroll
            for (int i = 0; i < 4; ++i) {
                const int idx = tid + i * 256;
                const int row = idx >> 4;
                const int col = (idx & 15) << 2;
                const float4 f = *(const float4*)(Kg + row * 64 + col);
                uint2 w; w.x = fpack2_fast(f.x, f.y); w.y = fpack2_fast(f.z, f.w);
                *(uint2*)(&Klds[row * KSTRIDE + col]) = w;
            }
        }
        {
            const float* Vg = Vb + (size_t)kt * 64 * D_DIM;
            #pragma unroll
            for (int it = 0; it < 2; ++it) {
                const int rp   = (tid & 15) + (it << 4);
                const int cg   = tid >> 4;
                const int row0 = rp * 2;
                const int col  = cg * 4;
                const float4 a = *(const float4*)(Vg + row0 * 64 + col);
                const float4 b = *(const float4*)(Vg + (row0 + 1) * 64 + col);
                *(unsigned int*)(&Vlds[(col + 0) * KSTRIDE + row0]) = fpack2_fast(a.x, b.x);
                *(unsigned int*)(&Vlds[(col + 1) * KSTRIDE + row0]) = fpack2_fast(a.y, b.y);
                *(unsigned int*)(&Vlds[(col + 2) * KSTRIDE + row0]) = fpack2_fast(a.z, b.z);
                *(unsigned int*)(&Vlds[(col + 3) * KSTRIDE + row0]) = fpack2_fast(a.w, b.w);
            }
        }
        __syncthreads();
        float4v st[4];
        #pragma unroll
        for (int ks = 0; ks < 4; ++ks) {
            const unsigned short* kr = &Klds[(ks * 16 + l16) * KSTRIDE + quad * 8];
            const short8 kf0 = *(const short8*)(kr);
            const short8 kf1 = *(const short8*)(kr + 32);
            float4v z = (float4v){0.f, 0.f, 0.f, 0.f};
            z = __builtin_amdgcn_mfma_f32_16x16x32_bf16(kf0, qf[0], z, 0, 0, 0);
            z = __builtin_amdgcn_mfma_f32_16x16x32_bf16(kf1, qf[1], z, 0, 0, 0);
            st[ks] = z;
        }
        short4v pf[4];
        #pragma unroll
        for (int ks = 0; ks < 4; ++ks) {
            const float p0 = __builtin_amdgcn_exp2f(st[ks][0]);
            const float p1 = __builtin_amdgcn_exp2f(st[ks][1]);
            const float p2 = __builtin_amdgcn_exp2f(st[ks][2]);
            const float p3 = __builtin_amdgcn_exp2f(st[ks][3]);
            l_acc += (p0 + p1) + (p2 + p3);
            uint2 u; u.x = fpack2_trunc(p0, p1); u.y = fpack2_trunc(p2, p3);
            pf[ks] = __builtin_bit_cast(short4v, u);
        }
        #pragma unroll
        for (int dt = 0; dt < 4; ++dt) {
            const unsigned short* vr = &Vlds[(dt * 16 + l16) * KSTRIDE + quad * 4];
            #pragma unroll
            for (int ks = 0; ks < 4; ++ks) {
                const short4v vf = *(const short4v*)(vr + ks * 16);
                acc[dt] = __builtin_amdgcn_mfma_f32_16x16x16bf16_1k(vf, pf[ks], acc[dt], 0, 0, 0);
            }
        }
    }
    float l = l_acc;
    l += __shfl_xor(l, 16, 64);
    l += __shfl_xor(l, 32, 64);
    const float inv = 1.0f / l;
    float* Or = out + ((size_t)bh * S_LEN + qg) * D_DIM;
    #pragma unroll
    for (int dt = 0; dt < 4; ++dt) {
        float4 o;
        o.x = acc[dt][0] * inv; o.y = acc[dt][1] * inv;
        o.z = acc[dt][2] * inv; o.w = acc[dt][3] * inv;
        *(float4*)(Or + dt * 16 + quad * 4) = o;
    }
}

extern "C" void kernel_launch(void* const* d_in, const int* in_sizes, int n_in,
                              void* d_out, int out_size, void* d_ws, size_t ws_size,
                              hipStream_t stream) {
    const float* q = (const float*)d_in[0];
    const float* k = (const float*)d_in[1];
    const float* v = (const float*)d_in[2];
    float* out = (float*)d_out;
    const size_t need = (size_t)2 * BH_N * S_LEN * D_DIM * sizeof(unsigned short);
    if (ws_size >= need) {
        unsigned short* kbf = (unsigned short*)d_ws;
        unsigned short* vtp = kbf + (size_t)BH_N * S_LEN * D_DIM;
        prep<<<dim3(4096), 256, 0, stream>>>(k, v, kbf, vtp);
        attn_fwd15<<<dim3((S_LEN / 128) * BH_N), 256, 0, stream>>>(q, kbf, vtp, out);
    } else {
        attn_fwd<<<dim3(S_LEN / 64, BH_N), 256, 0, stream>>>(q, k, v, out);
    }
}